// Round 2
// baseline (973.455 us; speedup 1.0000x reference)
//
#include <hip/hip_runtime.h>
#include <stdint.h>

typedef __attribute__((ext_vector_type(8))) short bf16x8;
typedef __attribute__((ext_vector_type(4))) float f32x4;

#define DIM   4096
#define SEQ   2048
#define NH    32
#define NKV   8
#define HD    128
#define QKV_N 6144  /* 4096 q + 1024 k + 1024 v */
#define ATT_SCALE 0.08838834764831845f /* 1/sqrt(128) */

static __device__ __forceinline__ unsigned short f2bf_bits(float f) {
  uint32_t x = __builtin_bit_cast(uint32_t, f);
  x += 0x7fffu + ((x >> 16) & 1u);   // RNE; inputs finite
  return (unsigned short)(x >> 16);
}
static __device__ __forceinline__ float bf_bits2f(unsigned short u) {
  uint32_t x = ((uint32_t)u) << 16;
  return __builtin_bit_cast(float, x);
}

// ---------------------------------------------------------------------------
// fp32 in (R x C) -> bf16 out (C x R), 32x32 tiles via LDS.
// ---------------------------------------------------------------------------
__global__ __launch_bounds__(256) void transpose_f32_bf16(
    const float* __restrict__ in, unsigned short* __restrict__ out,
    int ld_in, int ld_out) {
  __shared__ unsigned short sh[32][33];
  const int c0 = blockIdx.x * 32, r0 = blockIdx.y * 32;
  const int t = threadIdx.x;
  const int cc = t & 31, rr = (t >> 5) * 4;
#pragma unroll
  for (int p = 0; p < 4; ++p)
    sh[cc][rr + p] = f2bf_bits(in[(size_t)(r0 + rr + p) * ld_in + (c0 + cc)]);
  __syncthreads();
#pragma unroll
  for (int p = 0; p < 4; ++p)
    out[(size_t)(c0 + rr + p) * ld_out + (r0 + cc)] = sh[rr + p][cc];
}

// bf16 in (R x C) -> bf16 out (C x R)
__global__ __launch_bounds__(256) void transpose_bf16(
    const unsigned short* __restrict__ in, unsigned short* __restrict__ out,
    int ld_in, int ld_out) {
  __shared__ unsigned short sh[32][33];
  const int c0 = blockIdx.x * 32, r0 = blockIdx.y * 32;
  const int t = threadIdx.x;
  const int cc = t & 31, rr = (t >> 5) * 4;
#pragma unroll
  for (int p = 0; p < 4; ++p)
    sh[cc][rr + p] = in[(size_t)(r0 + rr + p) * ld_in + (c0 + cc)];
  __syncthreads();
#pragma unroll
  for (int p = 0; p < 4; ++p)
    out[(size_t)(c0 + rr + p) * ld_out + (r0 + cc)] = sh[rr + p][cc];
}

// ---------------------------------------------------------------------------
// C(M,N) = A(M,K) @ Bt(N,K)^T.  A: fp32 or bf16 (A_FP32); Bt: bf16;
// C: fp32 or bf16 (OUT_FP32). fp32 accum. 128x128 tile, BK=32, 4 waves.
// ---------------------------------------------------------------------------
#define BM 128
#define BN 128
#define BK 32
#define LDSS 40  /* padded leading dim, 16B-aligned rows, conflict-free */

template <bool A_FP32, bool OUT_FP32>
__global__ __launch_bounds__(256) void gemm_bt(
    const void* __restrict__ A_, int lda,
    const unsigned short* __restrict__ Bt, int ldb,
    void* __restrict__ C_, int ldc, int K) {
  __shared__ __align__(16) unsigned short ldsA[BM * LDSS];
  __shared__ __align__(16) unsigned short ldsB[BN * LDSS];
  const int t = threadIdx.x;
  const int wave = t >> 6, lane = t & 63;
  const int lane16 = lane & 15, quad = lane >> 4;
  const int m0 = blockIdx.y * BM, n0 = blockIdx.x * BN;
  const int wrow = (wave >> 1) * 64, wcol = (wave & 1) * 64;

  f32x4 acc[4][4];
#pragma unroll
  for (int i = 0; i < 4; ++i)
#pragma unroll
    for (int j = 0; j < 4; ++j) acc[i][j] = (f32x4){0.f, 0.f, 0.f, 0.f};

  const int sr = t >> 2;         // 0..63
  const int sc = (t & 3) * 8;    // 0,8,16,24

  for (int kk = 0; kk < K; kk += BK) {
    __syncthreads();
#pragma unroll
    for (int i = 0; i < 2; ++i) {
      const int r = sr + i * 64;
      if (A_FP32) {
        const float* Af = (const float*)A_;
        const float4 a0 = *(const float4*)&Af[(size_t)(m0 + r) * lda + kk + sc];
        const float4 a1 = *(const float4*)&Af[(size_t)(m0 + r) * lda + kk + sc + 4];
        unsigned short* dst = &ldsA[r * LDSS + sc];
        dst[0] = f2bf_bits(a0.x); dst[1] = f2bf_bits(a0.y);
        dst[2] = f2bf_bits(a0.z); dst[3] = f2bf_bits(a0.w);
        dst[4] = f2bf_bits(a1.x); dst[5] = f2bf_bits(a1.y);
        dst[6] = f2bf_bits(a1.z); dst[7] = f2bf_bits(a1.w);
      } else {
        const unsigned short* Ab = (const unsigned short*)A_;
        *(bf16x8*)&ldsA[r * LDSS + sc] =
            *(const bf16x8*)&Ab[(size_t)(m0 + r) * lda + kk + sc];
      }
      *(bf16x8*)&ldsB[r * LDSS + sc] =
          *(const bf16x8*)&Bt[(size_t)(n0 + r) * ldb + kk + sc];
    }
    __syncthreads();

    bf16x8 af[4], bfr[4];
#pragma unroll
    for (int mi = 0; mi < 4; ++mi)
      af[mi] = *(const bf16x8*)&ldsA[(wrow + mi * 16 + lane16) * LDSS + quad * 8];
#pragma unroll
    for (int ni = 0; ni < 4; ++ni)
      bfr[ni] = *(const bf16x8*)&ldsB[(wcol + ni * 16 + lane16) * LDSS + quad * 8];
#pragma unroll
    for (int mi = 0; mi < 4; ++mi)
#pragma unroll
      for (int ni = 0; ni < 4; ++ni)
        acc[mi][ni] = __builtin_amdgcn_mfma_f32_16x16x32_bf16(
            af[mi], bfr[ni], acc[mi][ni], 0, 0, 0);
  }

  // C/D layout: col=lane&15, row=quad*4+reg  [m89 verified]
#pragma unroll
  for (int mi = 0; mi < 4; ++mi)
#pragma unroll
    for (int ni = 0; ni < 4; ++ni)
#pragma unroll
      for (int r = 0; r < 4; ++r) {
        const int row = m0 + wrow + mi * 16 + quad * 4 + r;
        const int col = n0 + wcol + ni * 16 + lane16;
        if (OUT_FP32)
          ((float*)C_)[(size_t)row * ldc + col] = acc[mi][ni][r];
        else
          ((unsigned short*)C_)[(size_t)row * ldc + col] = f2bf_bits(acc[mi][ni][r]);
      }
}

// ---------------------------------------------------------------------------
// Interleaved RoPE in place on qkv (2048 x 6144): q cols [0,4096), k cols
// [4096,5120). One thread per (pos, head, pair).
// ---------------------------------------------------------------------------
__global__ __launch_bounds__(256) void rope_kernel(unsigned short* __restrict__ qkv) {
  const int idx = blockIdx.x * 256 + threadIdx.x;       // 2048*40*64 total
  const int pos = idx / 2560;
  const int rem = idx - pos * 2560;
  const int head = rem >> 6;      // 0..39 (0..31 q, 32..39 k)
  const int i = rem & 63;         // pair index
  const float inv_freq = powf(10000.0f, -(float)(2 * i) / 128.0f);
  const float ang = (float)pos * inv_freq;
  const float c = cosf(ang), s = sinf(ang);
  const int col = (head < 32) ? head * 128 + 2 * i
                              : 4096 + (head - 32) * 128 + 2 * i;
  unsigned short* p = qkv + (size_t)pos * QKV_N + col;
  const float tr = bf_bits2f(p[0]), ti = bf_bits2f(p[1]);
  p[0] = f2bf_bits(tr * c - ti * s);
  p[1] = f2bf_bits(tr * s + ti * c);
}

// ---------------------------------------------------------------------------
// Flash attention: 1 wave per (head, 16 q-rows). Online softmax.
// Q,K from roped qkv; V from pre-transposed vT[kvh][d][s].
// ---------------------------------------------------------------------------
__global__ __launch_bounds__(64) void attn_kernel(
    const unsigned short* __restrict__ qkv,
    const unsigned short* __restrict__ vT,
    unsigned short* __restrict__ attn) {
  __shared__ __align__(16) unsigned short p_lds[16 * 40];
  const int lane = threadIdx.x;
  const int lane16 = lane & 15, quad = lane >> 4;
  const int h = blockIdx.y;
  const int q0 = blockIdx.x * 16;
  const int kvh = h >> 2;

  const unsigned short* qbase = qkv + (size_t)q0 * QKV_N + h * HD;
  const unsigned short* kbase = qkv + 4096 + kvh * HD;
  const unsigned short* vbase = vT + (size_t)kvh * HD * SEQ;

  // Q A-fragments: A[m=lane16][k=quad*8+j], 4 chunks of K-dim 32
  bf16x8 qf[4];
#pragma unroll
  for (int dc = 0; dc < 4; ++dc)
    qf[dc] = *(const bf16x8*)&qbase[(size_t)lane16 * QKV_N + dc * 32 + quad * 8];

  f32x4 o[8];
#pragma unroll
  for (int i = 0; i < 8; ++i) o[i] = (f32x4){0.f, 0.f, 0.f, 0.f};
  float mrow[4] = {-INFINITY, -INFINITY, -INFINITY, -INFINITY};
  float lrow[4] = {0.f, 0.f, 0.f, 0.f};

  const int nkb = (q0 + 16 + 31) >> 5;   // causal: keys 0 .. q0+15
  for (int kb = 0; kb < nkb; ++kb) {
    const int key0 = kb * 32;
    f32x4 S[2];
#pragma unroll
    for (int kt = 0; kt < 2; ++kt) {
      f32x4 sacc = (f32x4){0.f, 0.f, 0.f, 0.f};
#pragma unroll
      for (int dc = 0; dc < 4; ++dc) {
        const bf16x8 kf = *(const bf16x8*)&kbase[
            (size_t)(key0 + kt * 16 + lane16) * QKV_N + dc * 32 + quad * 8];
        sacc = __builtin_amdgcn_mfma_f32_16x16x32_bf16(qf[dc], kf, sacc, 0, 0, 0);
      }
      S[kt] = sacc;
    }

    float p[2][4], alpha[4];
#pragma unroll
    for (int r = 0; r < 4; ++r) {
      const int qrow = q0 + quad * 4 + r;
      float s0 = (key0 + lane16      <= qrow) ? S[0][r] * ATT_SCALE : -INFINITY;
      float s1 = (key0 + 16 + lane16 <= qrow) ? S[1][r] * ATT_SCALE : -INFINITY;
      float mx = fmaxf(s0, s1);
#pragma unroll
      for (int msk = 1; msk < 16; msk <<= 1) mx = fmaxf(mx, __shfl_xor(mx, msk, 64));
      const float newm = fmaxf(mrow[r], mx);
      alpha[r] = expf(mrow[r] - newm);   // expf(-inf)=0 on first block
      mrow[r] = newm;
      const float p0 = expf(s0 - newm);
      const float p1 = expf(s1 - newm);
      p[0][r] = p0; p[1][r] = p1;
      float rs = p0 + p1;
#pragma unroll
      for (int msk = 1; msk < 16; msk <<= 1) rs += __shfl_xor(rs, msk, 64);
      lrow[r] = lrow[r] * alpha[r] + rs;
    }
#pragma unroll
    for (int dt = 0; dt < 8; ++dt)
#pragma unroll
      for (int r = 0; r < 4; ++r) o[dt][r] *= alpha[r];

    // P: C-layout -> LDS -> A-layout  [m120-verified transform]
#pragma unroll
    for (int kt = 0; kt < 2; ++kt)
#pragma unroll
      for (int r = 0; r < 4; ++r)
        p_lds[(quad * 4 + r) * 40 + kt * 16 + lane16] = f2bf_bits(p[kt][r]);
    __syncthreads();
    const bf16x8 pf = *(const bf16x8*)&p_lds[lane16 * 40 + quad * 8];
#pragma unroll
    for (int dt = 0; dt < 8; ++dt) {
      const bf16x8 vf = *(const bf16x8*)&vbase[
          (size_t)(dt * 16 + lane16) * SEQ + key0 + quad * 8];
      o[dt] = __builtin_amdgcn_mfma_f32_16x16x32_bf16(pf, vf, o[dt], 0, 0, 0);
    }
    __syncthreads();
  }

#pragma unroll
  for (int r = 0; r < 4; ++r) {
    const float inv_l = 1.0f / lrow[r];
    const int qrow = q0 + quad * 4 + r;
    unsigned short* dst = attn + (size_t)qrow * DIM + h * HD;
#pragma unroll
    for (int dt = 0; dt < 8; ++dt)
      dst[dt * 16 + lane16] = f2bf_bits(o[dt][r] * inv_l);
  }
}

// ---------------------------------------------------------------------------
extern "C" void kernel_launch(void* const* d_in, const int* in_sizes, int n_in,
                              void* d_out, int out_size, void* d_ws, size_t ws_size,
                              hipStream_t stream) {
  const float* x  = (const float*)d_in[0];
  const float* wq = (const float*)d_in[1];
  const float* wk = (const float*)d_in[2];
  const float* wv = (const float*)d_in[3];
  const float* wo = (const float*)d_in[4];
  float* out = (float*)d_out;

  // Workspace (bf16 elements). woT aliases wqkvT (dead after GEMM1).
  unsigned short* wqkvT = (unsigned short*)d_ws;             // 6144*4096
  unsigned short* woT   = wqkvT;                             // 4096*4096 (alias)
  unsigned short* qkv   = wqkvT + (size_t)6144 * 4096;       // 2048*6144
  unsigned short* vT    = qkv   + (size_t)2048 * 6144;       // 1024*2048
  unsigned short* attn  = vT    + (size_t)1024 * 2048;       // 2048*4096
  // total: 48.25M shorts = 96.5 MB

  const dim3 b256(256);
  // Weight transposes (fp32->bf16): wqkvT rows [0,4096)=wqT, [4096,5120)=wkT, [5120,6144)=wvT
  transpose_f32_bf16<<<dim3(128, 128), b256, 0, stream>>>(wq, wqkvT, 4096, 4096);
  transpose_f32_bf16<<<dim3(32, 128),  b256, 0, stream>>>(wk, wqkvT + (size_t)4096 * 4096, 1024, 4096);
  transpose_f32_bf16<<<dim3(32, 128),  b256, 0, stream>>>(wv, wqkvT + (size_t)5120 * 4096, 1024, 4096);

  // Fused QKV projection: x(fp32 2048x4096) @ wqkvT^T -> qkv (bf16 2048x6144)
  gemm_bt<true, false><<<dim3(QKV_N / BN, SEQ / BM), b256, 0, stream>>>(
      x, DIM, wqkvT, DIM, qkv, QKV_N, DIM);

  // RoPE in place on q,k columns
  rope_kernel<<<dim3((SEQ * 2560) / 256), b256, 0, stream>>>(qkv);

  // V transpose: qkv v-cols (2048x1024, ld 6144) -> vT (1024x2048)
  transpose_bf16<<<dim3(32, 64), b256, 0, stream>>>(qkv + 5120, vT, 6144, 2048);

  // Attention: grid (q-blocks of 16, heads)
  attn_kernel<<<dim3(SEQ / 16, NH), dim3(64), 0, stream>>>(qkv, vT, attn);

  // wo transpose (fp32->bf16) into the now-dead wqkvT region
  transpose_f32_bf16<<<dim3(128, 128), b256, 0, stream>>>(wo, woT, 4096, 4096);

  // Output projection: attn(bf16) @ woT^T -> out (fp32)
  gemm_bt<false, true><<<dim3(DIM / BN, SEQ / BM), b256, 0, stream>>>(
      attn, DIM, woT, DIM, out, DIM, DIM);
}

// Round 3
// 741.906 us; speedup vs baseline: 1.3121x; 1.3121x over previous
//
#include <hip/hip_runtime.h>
#include <stdint.h>

typedef __attribute__((ext_vector_type(8))) short bf16x8;
typedef __attribute__((ext_vector_type(4))) float f32x4;

#define DIM   4096
#define SEQ   2048
#define NH    32
#define NKV   8
#define HD    128
#define QKV_N 6144  /* 4096 q + 1024 k + 1024 v */
#define ATT_SCALE 0.08838834764831845f /* 1/sqrt(128) */

static __device__ __forceinline__ unsigned short f2bf_bits(float f) {
  uint32_t x = __builtin_bit_cast(uint32_t, f);
  x += 0x7fffu + ((x >> 16) & 1u);   // RNE; inputs finite
  return (unsigned short)(x >> 16);
}
static __device__ __forceinline__ float bf_bits2f(unsigned short u) {
  uint32_t x = ((uint32_t)u) << 16;
  return __builtin_bit_cast(float, x);
}

// ---------------------------------------------------------------------------
// fp32 in (R x C) -> bf16 out (C x R), 32x32 tiles via LDS.
// ---------------------------------------------------------------------------
__global__ __launch_bounds__(256) void transpose_f32_bf16(
    const float* __restrict__ in, unsigned short* __restrict__ out,
    int ld_in, int ld_out) {
  __shared__ unsigned short sh[32][33];
  const int c0 = blockIdx.x * 32, r0 = blockIdx.y * 32;
  const int t = threadIdx.x;
  const int cc = t & 31, rr = (t >> 5) * 4;
#pragma unroll
  for (int p = 0; p < 4; ++p)
    sh[cc][rr + p] = f2bf_bits(in[(size_t)(r0 + rr + p) * ld_in + (c0 + cc)]);
  __syncthreads();
#pragma unroll
  for (int p = 0; p < 4; ++p)
    out[(size_t)(c0 + rr + p) * ld_out + (r0 + cc)] = sh[rr + p][cc];
}

// bf16 in (R x C) -> bf16 out (C x R)
__global__ __launch_bounds__(256) void transpose_bf16(
    const unsigned short* __restrict__ in, unsigned short* __restrict__ out,
    int ld_in, int ld_out) {
  __shared__ unsigned short sh[32][33];
  const int c0 = blockIdx.x * 32, r0 = blockIdx.y * 32;
  const int t = threadIdx.x;
  const int cc = t & 31, rr = (t >> 5) * 4;
#pragma unroll
  for (int p = 0; p < 4; ++p)
    sh[cc][rr + p] = in[(size_t)(r0 + rr + p) * ld_in + (c0 + cc)];
  __syncthreads();
#pragma unroll
  for (int p = 0; p < 4; ++p)
    out[(size_t)(c0 + rr + p) * ld_out + (r0 + cc)] = sh[rr + p][cc];
}

// ---------------------------------------------------------------------------
// C(M,N) = A(M,K) @ Bt(N,K)^T.  A: fp32 or bf16; C: fp32 or bf16.
// 128x128 tile, BK=32, 4 waves, mfma_f32_16x16x32_bf16.
// ---------------------------------------------------------------------------
#define BM 128
#define BN 128
#define BK 32
#define LDSS 40

template <bool A_FP32, bool OUT_FP32>
__global__ __launch_bounds__(256) void gemm_bt(
    const void* __restrict__ A_, int lda,
    const unsigned short* __restrict__ Bt, int ldb,
    void* __restrict__ C_, int ldc, int K) {
  __shared__ __align__(16) unsigned short ldsA[BM * LDSS];
  __shared__ __align__(16) unsigned short ldsB[BN * LDSS];
  const int t = threadIdx.x;
  const int wave = t >> 6, lane = t & 63;
  const int lane16 = lane & 15, quad = lane >> 4;
  const int m0 = blockIdx.y * BM, n0 = blockIdx.x * BN;
  const int wrow = (wave >> 1) * 64, wcol = (wave & 1) * 64;

  f32x4 acc[4][4];
#pragma unroll
  for (int i = 0; i < 4; ++i)
#pragma unroll
    for (int j = 0; j < 4; ++j) acc[i][j] = (f32x4){0.f, 0.f, 0.f, 0.f};

  const int sr = t >> 2;
  const int sc = (t & 3) * 8;

  for (int kk = 0; kk < K; kk += BK) {
    __syncthreads();
#pragma unroll
    for (int i = 0; i < 2; ++i) {
      const int r = sr + i * 64;
      if (A_FP32) {
        const float* Af = (const float*)A_;
        const float4 a0 = *(const float4*)&Af[(size_t)(m0 + r) * lda + kk + sc];
        const float4 a1 = *(const float4*)&Af[(size_t)(m0 + r) * lda + kk + sc + 4];
        unsigned short* dst = &ldsA[r * LDSS + sc];
        dst[0] = f2bf_bits(a0.x); dst[1] = f2bf_bits(a0.y);
        dst[2] = f2bf_bits(a0.z); dst[3] = f2bf_bits(a0.w);
        dst[4] = f2bf_bits(a1.x); dst[5] = f2bf_bits(a1.y);
        dst[6] = f2bf_bits(a1.z); dst[7] = f2bf_bits(a1.w);
      } else {
        const unsigned short* Ab = (const unsigned short*)A_;
        *(bf16x8*)&ldsA[r * LDSS + sc] =
            *(const bf16x8*)&Ab[(size_t)(m0 + r) * lda + kk + sc];
      }
      *(bf16x8*)&ldsB[r * LDSS + sc] =
          *(const bf16x8*)&Bt[(size_t)(n0 + r) * ldb + kk + sc];
    }
    __syncthreads();

    bf16x8 af[4], bfr[4];
#pragma unroll
    for (int mi = 0; mi < 4; ++mi)
      af[mi] = *(const bf16x8*)&ldsA[(wrow + mi * 16 + lane16) * LDSS + quad * 8];
#pragma unroll
    for (int ni = 0; ni < 4; ++ni)
      bfr[ni] = *(const bf16x8*)&ldsB[(wcol + ni * 16 + lane16) * LDSS + quad * 8];
#pragma unroll
    for (int mi = 0; mi < 4; ++mi)
#pragma unroll
      for (int ni = 0; ni < 4; ++ni)
        acc[mi][ni] = __builtin_amdgcn_mfma_f32_16x16x32_bf16(
            af[mi], bfr[ni], acc[mi][ni], 0, 0, 0);
  }

#pragma unroll
  for (int mi = 0; mi < 4; ++mi)
#pragma unroll
    for (int ni = 0; ni < 4; ++ni)
#pragma unroll
      for (int r = 0; r < 4; ++r) {
        const int row = m0 + wrow + mi * 16 + quad * 4 + r;
        const int col = n0 + wcol + ni * 16 + lane16;
        if (OUT_FP32)
          ((float*)C_)[(size_t)row * ldc + col] = acc[mi][ni][r];
        else
          ((unsigned short*)C_)[(size_t)row * ldc + col] = f2bf_bits(acc[mi][ni][r]);
      }
}

// ---------------------------------------------------------------------------
// Interleaved RoPE in place on qkv.
// ---------------------------------------------------------------------------
__global__ __launch_bounds__(256) void rope_kernel(unsigned short* __restrict__ qkv) {
  const int idx = blockIdx.x * 256 + threadIdx.x;
  const int pos = idx / 2560;
  const int rem = idx - pos * 2560;
  const int head = rem >> 6;
  const int i = rem & 63;
  // 10000^(-2i/128) = exp(-(2i/128)*ln(10000))
  const float inv_freq = __expf(-(float)(2 * i) * (9.210340371976184f / 128.0f));
  const float ang = (float)pos * inv_freq;
  float s, c;
  __sincosf(ang, &s, &c);
  const int col = (head < 32) ? head * 128 + 2 * i
                              : 4096 + (head - 32) * 128 + 2 * i;
  unsigned short* p = qkv + (size_t)pos * QKV_N + col;
  const float tr = bf_bits2f(p[0]), ti = bf_bits2f(p[1]);
  p[0] = f2bf_bits(tr * c - ti * s);
  p[1] = f2bf_bits(tr * s + ti * c);
}

// ---------------------------------------------------------------------------
// Flash attention: 256-thread block = 4 waves; Q-tile 64 rows (16/wave);
// K/V tiles (64 keys) staged in LDS per block. Online softmax per wave.
// ---------------------------------------------------------------------------
#define QT 64
#define KT 64

__global__ __launch_bounds__(256) void attn_kernel(
    const unsigned short* __restrict__ qkv,
    const unsigned short* __restrict__ vT,
    unsigned short* __restrict__ attn) {
  __shared__ __align__(16) unsigned short kls[KT][HD + 8];      // 17408 B
  __shared__ __align__(16) unsigned short vls[HD][KT + 8];      // 18432 B
  __shared__ __align__(16) unsigned short pls[4][16][KT + 8];   //  9216 B

  const int t = threadIdx.x;
  const int wave = t >> 6, lane = t & 63;
  const int lane16 = lane & 15, quad = lane >> 4;
  const int h = blockIdx.y, kvh = h >> 2;
  const int qt = (gridDim.x - 1) - blockIdx.x;   // heavy q-tiles dispatch first
  const int q0 = qt * QT;
  const int wq0 = q0 + wave * 16;                // this wave's 16 q-rows

  const unsigned short* qbase = qkv + (size_t)wq0 * QKV_N + h * HD;
  const unsigned short* kbase = qkv + 4096 + kvh * HD;
  const unsigned short* vbase = vT + (size_t)kvh * HD * SEQ;

  // Q A-fragments: A[m=lane16][k=quad*8+j], 4 chunks of k=32
  bf16x8 qf[4];
#pragma unroll
  for (int dc = 0; dc < 4; ++dc)
    qf[dc] = *(const bf16x8*)&qbase[(size_t)lane16 * QKV_N + dc * 32 + quad * 8];

  f32x4 o[8];
#pragma unroll
  for (int i = 0; i < 8; ++i) o[i] = (f32x4){0.f, 0.f, 0.f, 0.f};
  float mrow[4] = {-INFINITY, -INFINITY, -INFINITY, -INFINITY};
  float lrow[4] = {0.f, 0.f, 0.f, 0.f};

  const int nkb = qt + 1;  // block-uniform causal bound: keys < (qt+1)*64
  for (int kb = 0; kb < nkb; ++kb) {
    const int key0 = kb * KT;
    __syncthreads();
    {  // stage K tile: 64 keys x 128 dims
      const int r = t >> 2, c = (t & 3) * 8;
      const unsigned short* src = &kbase[(size_t)(key0 + r) * QKV_N];
#pragma unroll
      for (int j = 0; j < 4; ++j)
        *(bf16x8*)&kls[r][c + j * 32] = *(const bf16x8*)&src[c + j * 32];
    }
    {  // stage V tile: 128 dims x 64 keys (from vT)
      const int d = t >> 1, s0 = (t & 1) * 32;
      const unsigned short* src = &vbase[(size_t)d * SEQ + key0];
#pragma unroll
      for (int j = 0; j < 4; ++j)
        *(bf16x8*)&vls[d][s0 + j * 8] = *(const bf16x8*)&src[s0 + j * 8];
    }
    __syncthreads();

    // QK^T: 4 sub-tiles of 16 keys
    f32x4 S[4];
#pragma unroll
    for (int kt = 0; kt < 4; ++kt) {
      f32x4 sacc = (f32x4){0.f, 0.f, 0.f, 0.f};
#pragma unroll
      for (int dc = 0; dc < 4; ++dc) {
        const bf16x8 kf = *(const bf16x8*)&kls[kt * 16 + lane16][dc * 32 + quad * 8];
        sacc = __builtin_amdgcn_mfma_f32_16x16x32_bf16(qf[dc], kf, sacc, 0, 0, 0);
      }
      S[kt] = sacc;
    }

    // online softmax (rows = quad*4+r across lanes 0..15 of each quad)
    float p[4][4], alpha[4];
#pragma unroll
    for (int r = 0; r < 4; ++r) {
      const int qrow = wq0 + quad * 4 + r;
      float s[4], mx = -INFINITY;
#pragma unroll
      for (int kt = 0; kt < 4; ++kt) {
        const int key = key0 + kt * 16 + lane16;
        s[kt] = (key <= qrow) ? S[kt][r] * ATT_SCALE : -INFINITY;
        mx = fmaxf(mx, s[kt]);
      }
#pragma unroll
      for (int msk = 1; msk < 16; msk <<= 1) mx = fmaxf(mx, __shfl_xor(mx, msk, 64));
      const float newm = fmaxf(mrow[r], mx);
      alpha[r] = __expf(mrow[r] - newm);   // 0 on first block
      mrow[r] = newm;
      float rs = 0.f;
#pragma unroll
      for (int kt = 0; kt < 4; ++kt) {
        p[kt][r] = __expf(s[kt] - newm);   // exp(-inf)=0 handles masked
        rs += p[kt][r];
      }
#pragma unroll
      for (int msk = 1; msk < 16; msk <<= 1) rs += __shfl_xor(rs, msk, 64);
      lrow[r] = lrow[r] * alpha[r] + rs;
    }
#pragma unroll
    for (int dt = 0; dt < 8; ++dt)
#pragma unroll
      for (int r = 0; r < 4; ++r) o[dt][r] *= alpha[r];

    // P: C-layout -> wave-private LDS -> A-layout (intra-wave, no barrier)
#pragma unroll
    for (int kt = 0; kt < 4; ++kt)
#pragma unroll
      for (int r = 0; r < 4; ++r)
        pls[wave][quad * 4 + r][kt * 16 + lane16] = f2bf_bits(p[kt][r]);
    const bf16x8 pf0 = *(const bf16x8*)&pls[wave][lane16][quad * 8];
    const bf16x8 pf1 = *(const bf16x8*)&pls[wave][lane16][32 + quad * 8];

    // PV: o += P(16x64) @ V^T(64 x 128-dims)
#pragma unroll
    for (int dt = 0; dt < 8; ++dt) {
      const bf16x8 vf0 = *(const bf16x8*)&vls[dt * 16 + lane16][quad * 8];
      const bf16x8 vf1 = *(const bf16x8*)&vls[dt * 16 + lane16][32 + quad * 8];
      o[dt] = __builtin_amdgcn_mfma_f32_16x16x32_bf16(pf0, vf0, o[dt], 0, 0, 0);
      o[dt] = __builtin_amdgcn_mfma_f32_16x16x32_bf16(pf1, vf1, o[dt], 0, 0, 0);
    }
  }

#pragma unroll
  for (int r = 0; r < 4; ++r) {
    const float inv_l = 1.0f / lrow[r];
    const int qrow = wq0 + quad * 4 + r;
    unsigned short* dst = attn + (size_t)qrow * DIM + h * HD;
#pragma unroll
    for (int dt = 0; dt < 8; ++dt)
      dst[dt * 16 + lane16] = f2bf_bits(o[dt][r] * inv_l);
  }
}

// ---------------------------------------------------------------------------
extern "C" void kernel_launch(void* const* d_in, const int* in_sizes, int n_in,
                              void* d_out, int out_size, void* d_ws, size_t ws_size,
                              hipStream_t stream) {
  const float* x  = (const float*)d_in[0];
  const float* wq = (const float*)d_in[1];
  const float* wk = (const float*)d_in[2];
  const float* wv = (const float*)d_in[3];
  const float* wo = (const float*)d_in[4];
  float* out = (float*)d_out;

  unsigned short* wqkvT = (unsigned short*)d_ws;             // 6144*4096
  unsigned short* woT   = wqkvT;                             // alias (dead after GEMM1)
  unsigned short* qkv   = wqkvT + (size_t)6144 * 4096;       // 2048*6144
  unsigned short* vT    = qkv   + (size_t)2048 * 6144;       // 1024*2048
  unsigned short* attn  = vT    + (size_t)1024 * 2048;       // 2048*4096

  const dim3 b256(256);
  transpose_f32_bf16<<<dim3(128, 128), b256, 0, stream>>>(wq, wqkvT, 4096, 4096);
  transpose_f32_bf16<<<dim3(32, 128),  b256, 0, stream>>>(wk, wqkvT + (size_t)4096 * 4096, 1024, 4096);
  transpose_f32_bf16<<<dim3(32, 128),  b256, 0, stream>>>(wv, wqkvT + (size_t)5120 * 4096, 1024, 4096);

  gemm_bt<true, false><<<dim3(QKV_N / BN, SEQ / BM), b256, 0, stream>>>(
      x, DIM, wqkvT, DIM, qkv, QKV_N, DIM);

  rope_kernel<<<dim3((SEQ * 2560) / 256), b256, 0, stream>>>(qkv);

  transpose_bf16<<<dim3(32, 64), b256, 0, stream>>>(qkv + 5120, vT, 6144, 2048);

  attn_kernel<<<dim3(SEQ / QT, NH), b256, 0, stream>>>(qkv, vT, attn);

  transpose_f32_bf16<<<dim3(128, 128), b256, 0, stream>>>(wo, woT, 4096, 4096);

  gemm_bt<false, true><<<dim3(DIM / BN, SEQ / BM), b256, 0, stream>>>(
      attn, DIM, woT, DIM, out, DIM, DIM);
}

// Round 4
// 616.852 us; speedup vs baseline: 1.5781x; 1.2027x over previous
//
#include <hip/hip_runtime.h>
#include <stdint.h>

typedef __attribute__((ext_vector_type(8))) short bf16x8;
typedef __attribute__((ext_vector_type(4))) short bf16x4;
typedef __attribute__((ext_vector_type(4))) float f32x4;
typedef __attribute__((ext_vector_type(4))) unsigned short u16x4;

#define DIM   4096
#define SEQ   2048
#define NH    32
#define NKV   8
#define HD    128
#define QKV_N 6144  /* 4096 q + 1024 k + 1024 v */
#define ATT_SCALE 0.08838834764831845f /* 1/sqrt(128) */

static __device__ __forceinline__ unsigned short f2bf_bits(float f) {
  uint32_t x = __builtin_bit_cast(uint32_t, f);
  x += 0x7fffu + ((x >> 16) & 1u);   // RNE; inputs finite
  return (unsigned short)(x >> 16);
}
static __device__ __forceinline__ float bf_bits2f(unsigned short u) {
  uint32_t x = ((uint32_t)u) << 16;
  return __builtin_bit_cast(float, x);
}

// ---------------------------------------------------------------------------
// fp32 (R x C) -> bf16 (C x R), 32x32 tiles via LDS.
// ---------------------------------------------------------------------------
__global__ __launch_bounds__(256) void transpose_f32_bf16(
    const float* __restrict__ in, unsigned short* __restrict__ out,
    int ld_in, int ld_out) {
  __shared__ unsigned short sh[32][33];
  const int c0 = blockIdx.x * 32, r0 = blockIdx.y * 32;
  const int t = threadIdx.x;
  const int cc = t & 31, rr = (t >> 5) * 4;
#pragma unroll
  for (int p = 0; p < 4; ++p)
    sh[cc][rr + p] = f2bf_bits(in[(size_t)(r0 + rr + p) * ld_in + (c0 + cc)]);
  __syncthreads();
#pragma unroll
  for (int p = 0; p < 4; ++p)
    out[(size_t)(c0 + rr + p) * ld_out + (r0 + cc)] = sh[rr + p][cc];
}

// bf16 (R x C) -> bf16 (C x R)
__global__ __launch_bounds__(256) void transpose_bf16(
    const unsigned short* __restrict__ in, unsigned short* __restrict__ out,
    int ld_in, int ld_out) {
  __shared__ unsigned short sh[32][33];
  const int c0 = blockIdx.x * 32, r0 = blockIdx.y * 32;
  const int t = threadIdx.x;
  const int cc = t & 31, rr = (t >> 5) * 4;
#pragma unroll
  for (int p = 0; p < 4; ++p)
    sh[cc][rr + p] = in[(size_t)(r0 + rr + p) * ld_in + (c0 + cc)];
  __syncthreads();
#pragma unroll
  for (int p = 0; p < 4; ++p)
    out[(size_t)(c0 + rr + p) * ld_out + (r0 + cc)] = sh[rr + p][cc];
}

// fp32 -> bf16 elementwise (x pre-conversion), 4 elems/thread
__global__ __launch_bounds__(256) void convert_f32_bf16(
    const float* __restrict__ in, unsigned short* __restrict__ out) {
  const int i = (blockIdx.x * 256 + threadIdx.x) * 4;
  const float4 v = *(const float4*)&in[i];
  u16x4 w;
  w[0] = f2bf_bits(v.x); w[1] = f2bf_bits(v.y);
  w[2] = f2bf_bits(v.z); w[3] = f2bf_bits(v.w);
  *(u16x4*)&out[i] = w;
}

// ---------------------------------------------------------------------------
// C(M,N) = A(M,K) @ Bt(N,K)^T.  bf16 in; C fp32 or bf16. 128x128, BK=32.
// ---------------------------------------------------------------------------
#define BM 128
#define BN 128
#define BK 32
#define LDSS 40

template <bool OUT_FP32>
__global__ __launch_bounds__(256) void gemm_bt(
    const unsigned short* __restrict__ A, int lda,
    const unsigned short* __restrict__ Bt, int ldb,
    void* __restrict__ C_, int ldc, int K) {
  __shared__ __align__(16) unsigned short ldsA[BM * LDSS];
  __shared__ __align__(16) unsigned short ldsB[BN * LDSS];
  const int t = threadIdx.x;
  const int wave = t >> 6, lane = t & 63;
  const int lane16 = lane & 15, quad = lane >> 4;
  const int m0 = blockIdx.y * BM, n0 = blockIdx.x * BN;
  const int wrow = (wave >> 1) * 64, wcol = (wave & 1) * 64;

  f32x4 acc[4][4];
#pragma unroll
  for (int i = 0; i < 4; ++i)
#pragma unroll
    for (int j = 0; j < 4; ++j) acc[i][j] = (f32x4){0.f, 0.f, 0.f, 0.f};

  const int sr = t >> 2;
  const int sc = (t & 3) * 8;

  for (int kk = 0; kk < K; kk += BK) {
    __syncthreads();
#pragma unroll
    for (int i = 0; i < 2; ++i) {
      const int r = sr + i * 64;
      *(bf16x8*)&ldsA[r * LDSS + sc] =
          *(const bf16x8*)&A[(size_t)(m0 + r) * lda + kk + sc];
      *(bf16x8*)&ldsB[r * LDSS + sc] =
          *(const bf16x8*)&Bt[(size_t)(n0 + r) * ldb + kk + sc];
    }
    __syncthreads();

    bf16x8 af[4], bfr[4];
#pragma unroll
    for (int mi = 0; mi < 4; ++mi)
      af[mi] = *(const bf16x8*)&ldsA[(wrow + mi * 16 + lane16) * LDSS + quad * 8];
#pragma unroll
    for (int ni = 0; ni < 4; ++ni)
      bfr[ni] = *(const bf16x8*)&ldsB[(wcol + ni * 16 + lane16) * LDSS + quad * 8];
#pragma unroll
    for (int mi = 0; mi < 4; ++mi)
#pragma unroll
      for (int ni = 0; ni < 4; ++ni)
        acc[mi][ni] = __builtin_amdgcn_mfma_f32_16x16x32_bf16(
            af[mi], bfr[ni], acc[mi][ni], 0, 0, 0);
  }

#pragma unroll
  for (int mi = 0; mi < 4; ++mi)
#pragma unroll
    for (int ni = 0; ni < 4; ++ni)
#pragma unroll
      for (int r = 0; r < 4; ++r) {
        const int row = m0 + wrow + mi * 16 + quad * 4 + r;
        const int col = n0 + wcol + ni * 16 + lane16;
        if (OUT_FP32)
          ((float*)C_)[(size_t)row * ldc + col] = acc[mi][ni][r];
        else
          ((unsigned short*)C_)[(size_t)row * ldc + col] = f2bf_bits(acc[mi][ni][r]);
      }
}

// ---------------------------------------------------------------------------
// Interleaved RoPE in place on qkv.
// ---------------------------------------------------------------------------
__global__ __launch_bounds__(256) void rope_kernel(unsigned short* __restrict__ qkv) {
  const int idx = blockIdx.x * 256 + threadIdx.x;
  const int pos = idx / 2560;
  const int rem = idx - pos * 2560;
  const int head = rem >> 6;
  const int i = rem & 63;
  const float inv_freq = __expf(-(float)(2 * i) * (9.210340371976184f / 128.0f));
  const float ang = (float)pos * inv_freq;
  float s, c;
  __sincosf(ang, &s, &c);
  const int col = (head < 32) ? head * 128 + 2 * i
                              : 4096 + (head - 32) * 128 + 2 * i;
  unsigned short* p = qkv + (size_t)pos * QKV_N + col;
  const float tr = bf_bits2f(p[0]), ti = bf_bits2f(p[1]);
  p[0] = f2bf_bits(tr * c - ti * s);
  p[1] = f2bf_bits(tr * s + ti * c);
}

// ---------------------------------------------------------------------------
// Flash attention, operand-swapped: S^T = K@Q^T via mfma(A=K,B=Q); the
// C-layout of S^T (q=lane16, s=quad*4+reg) IS the B-fragment layout of the
// K=16 MFMA, so PV = mfma_16x16x16(A=V^T, B=P-registers) with no LDS
// transform. O^T[d][q] accumulates in C-layout. m/l are per-lane scalars.
// ---------------------------------------------------------------------------
#define QT 64
#define KT 64
#define KLS (HD + 8)   /* 136 shorts, 16B-aligned rows */
#define VLS (KT + 8)   /* 72 shorts */

__global__ __launch_bounds__(256) void attn_kernel(
    const unsigned short* __restrict__ qkv,
    const unsigned short* __restrict__ vT,
    unsigned short* __restrict__ attn) {
  __shared__ __align__(16) unsigned short kls[KT][KLS];   // 17408 B
  __shared__ __align__(16) unsigned short vls[HD][VLS];   // 18432 B

  const int t = threadIdx.x;
  const int wave = t >> 6, lane = t & 63;
  const int lane16 = lane & 15, quad = lane >> 4;
  const int h = blockIdx.y, kvh = h >> 2;
  const int qt = (gridDim.x - 1) - blockIdx.x;   // heavy q-tiles first
  const int q0 = qt * QT;
  const int wq0 = q0 + wave * 16;
  const int qrow = wq0 + lane16;                 // this lane's q row

  const unsigned short* qbase = qkv + (size_t)wq0 * QKV_N + h * HD;
  const unsigned short* kbase = qkv + 4096 + kvh * HD;
  const unsigned short* vbase = vT + (size_t)kvh * HD * SEQ;

  // Q fragments (B-operand): B[n=lane16][k=quad*8+j]
  bf16x8 qf[4];
#pragma unroll
  for (int dc = 0; dc < 4; ++dc)
    qf[dc] = *(const bf16x8*)&qbase[(size_t)lane16 * QKV_N + dc * 32 + quad * 8];

  f32x4 o[8];  // O^T[d][q] accumulators, d = dt*16 + (quad*4+reg)
#pragma unroll
  for (int i = 0; i < 8; ++i) o[i] = (f32x4){0.f, 0.f, 0.f, 0.f};
  float m = -INFINITY, l = 0.f;

  const int nkb = qt + 1;
  for (int kb = 0; kb < nkb; ++kb) {
    const int key0 = kb * KT;
    __syncthreads();
    {  // stage K: 64 keys x 128 dims
      const int r = t >> 2, c = (t & 3) * 8;
      const unsigned short* src = &kbase[(size_t)(key0 + r) * QKV_N];
#pragma unroll
      for (int j = 0; j < 4; ++j)
        *(bf16x8*)&kls[r][c + j * 32] = *(const bf16x8*)&src[c + j * 32];
    }
    {  // stage V^T: 128 dims x 64 keys
      const int d = t >> 1, s0 = (t & 1) * 32;
      const unsigned short* src = &vbase[(size_t)d * SEQ + key0];
#pragma unroll
      for (int j = 0; j < 4; ++j)
        *(bf16x8*)&vls[d][s0 + j * 8] = *(const bf16x8*)&src[s0 + j * 8];
    }
    __syncthreads();

    // S^T[s][q]: A=K (m=s), B=Q (n=q); 4 key sub-tiles
    f32x4 S[4];
#pragma unroll
    for (int kt = 0; kt < 4; ++kt) {
      f32x4 sacc = (f32x4){0.f, 0.f, 0.f, 0.f};
#pragma unroll
      for (int dc = 0; dc < 4; ++dc) {
        const bf16x8 kf = *(const bf16x8*)&kls[kt * 16 + lane16][dc * 32 + quad * 8];
        sacc = __builtin_amdgcn_mfma_f32_16x16x32_bf16(kf, qf[dc], sacc, 0, 0, 0);
      }
      S[kt] = sacc;
    }

    // per-lane softmax over this lane's 16 s-values, reduce across quads
    float sv[4][4], mx = -INFINITY;
#pragma unroll
    for (int kt = 0; kt < 4; ++kt)
#pragma unroll
      for (int r = 0; r < 4; ++r) {
        const int key = key0 + kt * 16 + quad * 4 + r;
        sv[kt][r] = (key <= qrow) ? S[kt][r] * ATT_SCALE : -INFINITY;
        mx = fmaxf(mx, sv[kt][r]);
      }
    mx = fmaxf(mx, __shfl_xor(mx, 16, 64));
    mx = fmaxf(mx, __shfl_xor(mx, 32, 64));
    const float newm = fmaxf(m, mx);
    const float alpha = __expf(m - newm);   // 0 on first block
    m = newm;
    float p[4][4], rs = 0.f;
#pragma unroll
    for (int kt = 0; kt < 4; ++kt)
#pragma unroll
      for (int r = 0; r < 4; ++r) {
        p[kt][r] = __expf(sv[kt][r] - newm);  // exp(-inf)=0 for masked
        rs += p[kt][r];
      }
    rs += __shfl_xor(rs, 16, 64);
    rs += __shfl_xor(rs, 32, 64);
    l = l * alpha + rs;
#pragma unroll
    for (int dt = 0; dt < 8; ++dt)
#pragma unroll
      for (int r = 0; r < 4; ++r) o[dt][r] *= alpha;

    // pack P rows into B-fragments (already in-layout, registers only)
    bf16x4 pb[4];
#pragma unroll
    for (int kt = 0; kt < 4; ++kt) {
      bf16x4 w;
      w[0] = (short)f2bf_bits(p[kt][0]); w[1] = (short)f2bf_bits(p[kt][1]);
      w[2] = (short)f2bf_bits(p[kt][2]); w[3] = (short)f2bf_bits(p[kt][3]);
      pb[kt] = w;
    }

    // O^T += V^T @ P : K=16 MFMA, A=V^T-frag (m=d, k=s), B=P (n=q, k=s)
#pragma unroll
    for (int dt = 0; dt < 8; ++dt)
#pragma unroll
      for (int kt = 0; kt < 4; ++kt) {
        const bf16x4 vf = *(const bf16x4*)&vls[dt * 16 + lane16][kt * 16 + quad * 4];
        o[dt] = __builtin_amdgcn_mfma_f32_16x16x16bf16_1k(vf, pb[kt], o[dt], 0, 0, 0);
      }
  }

  const float inv_l = 1.0f / l;
  unsigned short* dst = attn + (size_t)qrow * DIM + h * HD;
#pragma unroll
  for (int dt = 0; dt < 8; ++dt) {
    u16x4 w;
#pragma unroll
    for (int r = 0; r < 4; ++r) w[r] = f2bf_bits(o[dt][r] * inv_l);
    *(u16x4*)&dst[dt * 16 + quad * 4] = w;   // 8B-aligned
  }
}

// ---------------------------------------------------------------------------
extern "C" void kernel_launch(void* const* d_in, const int* in_sizes, int n_in,
                              void* d_out, int out_size, void* d_ws, size_t ws_size,
                              hipStream_t stream) {
  const float* x  = (const float*)d_in[0];
  const float* wq = (const float*)d_in[1];
  const float* wk = (const float*)d_in[2];
  const float* wv = (const float*)d_in[3];
  const float* wo = (const float*)d_in[4];
  float* out = (float*)d_out;

  unsigned short* wqkvT = (unsigned short*)d_ws;             // 6144*4096
  unsigned short* woT   = wqkvT;                             // alias (dead after GEMM1)
  unsigned short* qkv   = wqkvT + (size_t)6144 * 4096;       // 2048*6144
  unsigned short* vT    = qkv   + (size_t)2048 * 6144;       // 1024*2048
  unsigned short* attn  = vT    + (size_t)1024 * 2048;       // 2048*4096
  unsigned short* xb    = attn;                              // alias: xb dead before attn written

  const dim3 b256(256);
  transpose_f32_bf16<<<dim3(128, 128), b256, 0, stream>>>(wq, wqkvT, 4096, 4096);
  transpose_f32_bf16<<<dim3(32, 128),  b256, 0, stream>>>(wk, wqkvT + (size_t)4096 * 4096, 1024, 4096);
  transpose_f32_bf16<<<dim3(32, 128),  b256, 0, stream>>>(wv, wqkvT + (size_t)5120 * 4096, 1024, 4096);
  convert_f32_bf16<<<dim3(SEQ * DIM / 1024), b256, 0, stream>>>(x, xb);

  gemm_bt<false><<<dim3(QKV_N / BN, SEQ / BM), b256, 0, stream>>>(
      xb, DIM, wqkvT, DIM, qkv, QKV_N, DIM);

  rope_kernel<<<dim3((SEQ * 2560) / 256), b256, 0, stream>>>(qkv);

  transpose_bf16<<<dim3(32, 64), b256, 0, stream>>>(qkv + 5120, vT, 6144, 2048);

  attn_kernel<<<dim3(SEQ / QT, NH), b256, 0, stream>>>(qkv, vT, attn);

  transpose_f32_bf16<<<dim3(128, 128), b256, 0, stream>>>(wo, woT, 4096, 4096);

  gemm_bt<true><<<dim3(DIM / BN, SEQ / BM), b256, 0, stream>>>(
      attn, DIM, woT, DIM, out, DIM, DIM);
}